// Round 8
// baseline (191.180 us; speedup 1.0000x reference)
//
#include <hip/hip_runtime.h>

#define EDGES   262144
#define CTPB    256
#define SCHUNK  256
#define RTILE   512
#define NINT    1024   // 16 rblocks(512 recv each) * 8 schunks * 8 segments
#define NFLT    (EDGES / CTPB)   // 1024
#define NPRI    16     // 4096 nodes / 256
#define NBLK    (NINT + NFLT + NPRI)

typedef float v2f __attribute__((ext_vector_type(2)));

__device__ __forceinline__ float fast_rsq(float x) { return __builtin_amdgcn_rsqf(x); }

// Odd deg-9 erf approx, |x| clamped to 2 (erf(2)=0.9953); max abs err ~7e-4.
__device__ __forceinline__ float erf_poly(float x) {
    float c = __builtin_amdgcn_fmed3f(x, -2.0f, 2.0f);
    float t = c * c;
    float p = fmaf(t, fmaf(t, fmaf(t, fmaf(t, 0.0011996f, -0.0165450f),
                                   0.100174f), -0.370237f), 1.127915f);
    return c * p;
}

// r3-exact per-pair term: w=s0-r0, v=ds-dr; D=|w|^2, S=|v|^2, u=C*rsq
// term = exp(u^2-D)*rsq*(erf(rt-u)+erf(u)); self/degenerate pairs masked.
__device__ __forceinline__ float pterm(float szx, float szy, float sdx, float sdy,
                                       float rzx, float rzy, float rdx, float rdy,
                                       float acc) {
    float wx = szx - rzx, wy = szy - rzy;
    float vx = sdx - rdx, vy = sdy - rdy;
    float D  = fmaf(wy, wy, wx * wx);
    float S  = fmaf(vy, vy, vx * vx);
    float mc = fmaf(vy, wy, vx * wx);          // <v,w> = -C
    float rsq = fast_rsq(S);
    float u  = -mc * rsq;                      // C * rsq
    float rt = S * rsq;                        // sqrt(S)
    float ex = __expf(fmaf(u, u, -D));
    float e  = erf_poly(rt - u) + erf_poly(u);
    float q  = ex * rsq * e;
    float qm = (fminf(D, S) > 0.0f) ? q : 0.0f;
    return acc + qm;
}

template <int NW>
__device__ __forceinline__ float block_reduce(float v, float* sm) {
    #pragma unroll
    for (int o = 32; o > 0; o >>= 1) v += __shfl_down(v, o, 64);
    int lane = threadIdx.x & 63;
    int wid  = threadIdx.x >> 6;
    if (lane == 0) sm[wid] = v;
    __syncthreads();
    float r = 0.0f;
    if (threadIdx.x == 0) {
        #pragma unroll
        for (int w = 0; w < NW; ++w) r += sm[w];
    }
    return r;
}

// Single dispatch. ws: u32 counter @0, float acc[3] @ +16 (memset 32 B).
// Blocks [0,NINT): integral (512 receivers/block, 2 per thread);
// [NINT,+NFLT): edge term; rest: prior. Last finishing block finalizes.
__global__ __launch_bounds__(CTPB) void k_all(const float* __restrict__ Z,
        const float* __restrict__ ts, const int* __restrict__ snd,
        const int* __restrict__ rcv, const int* __restrict__ nodes,
        const int* __restrict__ su, const float* __restrict__ cp,
        const float* __restrict__ betap, const int* __restrict__ fsp,
        unsigned* __restrict__ ws, float* __restrict__ out,
        float n_entries, float bs) {
    __shared__ __align__(16) float sZx[SCHUNK];
    __shared__ __align__(16) float sZy[SCHUNK];
    __shared__ __align__(16) float sDx[SCHUNK];
    __shared__ __align__(16) float sDy[SCHUNK];
    __shared__ float smr[CTPB / 64];
    __shared__ int isLast;
    float* acc = (float*)(ws + 4);
    const int bid = blockIdx.x;
    const int tid = threadIdx.x;
    float r;
    int slot;

    if (bid < NINT) {
        const int k  = bid >> 7;
        const int sc = (bid >> 4) & 7;
        const int rb = bid & 15;
        {   // stage sender chunk (op forms MUST match receiver path)
            int n = su[sc * SCHUNK + tid];
            const float* z = Z + n * 18 + k;
            float zx = z[0], zy = z[9];
            sZx[tid] = zx; sZy[tid] = zy;
            sDx[tid] = z[1] - zx; sDy[tid] = z[10] - zy;
        }
        // two receivers per thread: j and j+256
        const float* zr0 = Z + (rb * RTILE + tid) * 18 + k;
        const float* zr1 = zr0 + 256 * 18;
        float r0zx = zr0[0], r0zy = zr0[9];
        float r0dx = zr0[1] - r0zx, r0dy = zr0[10] - r0zy;
        float r1zx = zr1[0], r1zy = zr1[9];
        float r1dx = zr1[1] - r1zx, r1dy = zr1[10] - r1zy;
        __syncthreads();

        const v2f* pZx = (const v2f*)sZx;
        const v2f* pZy = (const v2f*)sZy;
        const v2f* pDx = (const v2f*)sDx;
        const v2f* pDy = (const v2f*)sDy;
        float a00 = 0.0f, a01 = 0.0f, a10 = 0.0f, a11 = 0.0f;
        #pragma unroll 2
        for (int i = 0; i < SCHUNK / 2; ++i) {
            v2f azx = pZx[i];
            v2f azy = pZy[i];
            v2f adx = pDx[i];
            v2f ady = pDy[i];
            a00 = pterm(azx.x, azy.x, adx.x, ady.x, r0zx, r0zy, r0dx, r0dy, a00);
            a01 = pterm(azx.y, azy.y, adx.y, ady.y, r0zx, r0zy, r0dx, r0dy, a01);
            a10 = pterm(azx.x, azy.x, adx.x, ady.x, r1zx, r1zy, r1dx, r1dy, a10);
            a11 = pterm(azx.y, azy.y, adx.y, ady.y, r1zx, r1zy, r1dx, r1dy, a11);
        }
        r = block_reduce<CTPB / 64>((a00 + a01) + (a10 + a11), smr);
        slot = 2;
    } else if (bid < NINT + NFLT) {
        // ---- edge likelihood: -|od*(Zs_c-Zr_c) + d*(Zs_n-Zr_n)|^2 ----
        int e = (bid - NINT) * CTPB + tid;
        float seg = cp[1] - cp[0];
        float x   = ts[e] / seg;
        float kf  = floorf(x);
        int kappa = (int)kf;
        float d   = x - kf;
        float od  = 1.0f - d;
        int sb = snd[e] * 18, rbse = rcv[e] * 18;
        float ux = Z[sb + kappa]     - Z[rbse + kappa];
        float uy = Z[sb + 9 + kappa] - Z[rbse + 9 + kappa];
        float vx = Z[sb + kappa + 1]     - Z[rbse + kappa + 1];
        float vy = Z[sb + 9 + kappa + 1] - Z[rbse + 9 + kappa + 1];
        float wx = od * ux + d * vx;
        float wy = od * uy + d * vy;
        r = block_reduce<CTPB / 64>(-fmaf(wx, wx, wy * wy), smr);
        slot = 1;
    } else {
        // ---- prior ----
        int i = (bid - NINT - NFLT) * CTPB + tid;
        int n = nodes[i];
        const float* z = Z + n * 18;
        float s = 0.0f;
        #pragma unroll
        for (int d = 0; d < 2; ++d) {
            float prev = z[d * 9];
            s = fmaf(prev, prev, s);
            #pragma unroll
            for (int k = 1; k <= 8; ++k) {
                float cur = z[d * 9 + k];
                float df  = cur - prev;
                s = fmaf(df, df, s);
                prev = cur;
            }
        }
        r = block_reduce<CTPB / 64>(s, smr);
        slot = 0;
    }

    if (tid == 0) {
        atomicAdd(acc + slot, r);
        __threadfence();
        unsigned old = atomicAdd(ws, 1u);
        isLast = (old == NBLK - 1);
    }
    __syncthreads();
    if (isLast && tid == 0) {
        __threadfence();
        float pr = acc[0], fl = acc[1], qq = acc[2];
        float prior = 10.0f * pr;
        float beta  = betap[0];
        float fs    = (float)fsp[0];
        float seg   = cp[1] - cp[0];
        // integral = 0.5(scan) * 0.5(erf pair) * sqrt(0.5)(sigma) * dt * Q
        float integral = 0.17677669529663687f * seg * qq;
        const float sqrt2pi = 2.5066282746310002f;
        float res = prior - beta * n_entries - fl + sqrt2pi * expf(beta) * integral;
        out[0] = (fs / bs) * res;
    }
}

extern "C" void kernel_launch(void* const* d_in, const int* in_sizes, int n_in,
                              void* d_out, int out_size, void* d_ws, size_t ws_size,
                              hipStream_t stream) {
    const float* Z    = (const float*)d_in[0];
    const float* beta = (const float*)d_in[1];
    const float* ts   = (const float*)d_in[2];
    const int*   snd  = (const int*)d_in[3];
    const int*   rcv  = (const int*)d_in[4];
    const int*   nodes= (const int*)d_in[5];
    const int*   su   = (const int*)d_in[6];
    const float* cp   = (const float*)d_in[7];
    const int*   fs   = (const int*)d_in[8];

    (void)hipMemsetAsync(d_ws, 0, 32, stream);
    k_all<<<NBLK, CTPB, 0, stream>>>(Z, ts, snd, rcv, nodes, su, cp, beta, fs,
                                     (unsigned*)d_ws, (float*)d_out,
                                     (float)in_sizes[2], (float)in_sizes[5]);
}